// Round 10
// baseline (60.004 us; speedup 1.0000x reference)
//
#include <hip/hip_runtime.h>

#define N_EL   15
#define NPAIR  105
#define NPAD   112
#define BASIS  64
#define CUTOFF 10.0f
#define LOG2E  1.44269504088896340736f
#define LN2    0.69314718055994530942f
#define WPB    4        // waves (= problems) per block
#define NTHR   256

typedef float f32x2 __attribute__((ext_vector_type(2)));
typedef float f32x4 __attribute__((ext_vector_type(4)));
typedef short bf16x8 __attribute__((ext_vector_type(8)));
typedef int   i32x4  __attribute__((ext_vector_type(4)));

// packed 2xf32 -> 2xbf16 (RNE), one instruction
__device__ __forceinline__ int cvt_pk_bf16(float lo, float hi) {
    int r;
    asm("v_cvt_pk_bf16_f32 %0, %1, %2" : "=v"(r) : "v"(lo), "v"(hi));
    return r;
}

// shifted softplus: log(0.5 + 0.5*e^x)
__device__ __forceinline__ float ssp(float x) {
    float u = __builtin_amdgcn_exp2f(x * LOG2E);
    return LN2 * __builtin_amdgcn_logf(fmaf(0.5f, u, 0.5f));
}

__global__ __launch_bounds__(NTHR, 4)
void backflow_kernel(const float* __restrict__ rs,
                     const float* __restrict__ W0,
                     const float* __restrict__ b0,
                     const float* __restrict__ W1,
                     const float* __restrict__ b1,
                     const float* __restrict__ W2,
                     float* __restrict__ out) {
    // per-wave private LDS (wave-synchronous; no __syncthreads anywhere)
    __shared__ f32x2 s_dd[WPB][NPAD];   // (dist, env) per pair
    __shared__ f32x4 s_df[WPB][NPAD];   // (dx,dy,dz,_) -> overwritten by w*diff
    __shared__ f32x4 s_h2[WPB][NPAD];   // raw layer-1 MFMA output per pair
    __shared__ float s_xs[WPB][48];     // coordinates

    const int tid  = threadIdx.x;
    const int q    = tid >> 6;          // wave within block
    const int lane = tid & 63;
    const int g    = lane >> 4;         // 4-lane group
    const int col  = lane & 15;
    const int prob = blockIdx.x * WPB + q;

    // ---- per-lane basis constants: dim(ks,e) = ks*32 + (e>>2)*16 + g*4 + (e&3) ----
    f32x2 mu2[8], is2[8];               // [ks*4 + p], elem pair (2p, 2p+1)
    #pragma unroll
    for (int ks = 0; ks < 2; ++ks)
        #pragma unroll
        for (int p = 0; p < 4; ++p) {
            f32x2 m, s;
            #pragma unroll
            for (int h = 0; h < 2; ++h) {
                int dim = ks * 32 + (p >> 1) * 16 + g * 4 + (p & 1) * 2 + h;
                float qq = (float)(2 * dim + 1) * (1.0f / 128.0f);
                m[h] = CUTOFF * qq * qq;
                float sg = fmaf(CUTOFF, qq, 1.0f) * (1.0f / 7.0f);
                s[h] = -LOG2E / (sg * sg);
            }
            mu2[ks * 4 + p] = m;
            is2[ks * 4 + p] = s;
        }

    // ---- pair decode: p0 = lane, p1 = 64+lane (lane < 41) ----
    int pi0, pj0, pi1 = 0, pj1 = 0;
    {
        int t = lane, i = 0;
        while (t >= N_EL - 1 - i) { t -= N_EL - 1 - i; ++i; }
        pi0 = i; pj0 = i + 1 + t;
    }
    if (lane < 41) {
        int t = 64 + lane, i = 0;
        while (t >= N_EL - 1 - i) { t -= N_EL - 1 - i; ++i; }
        pi1 = i; pj1 = i + 1 + t;
    }

    if (lane < 45) s_xs[q][lane] = rs[prob * 45 + lane];

    for (int k = 0; k < 3; ++k) {
        // ---- per-interaction weight fragments (L2-hot reload; low VGPR) ----
        bf16x8 w0f[2];      // A = W0^T : lane holds W0[dim(ks,e)][col]
        #pragma unroll
        for (int ks = 0; ks < 2; ++ks) {
            i32x4 wv;
            #pragma unroll
            for (int i = 0; i < 4; ++i) {
                int e0 = 2 * i, e1 = 2 * i + 1;
                int dim0 = ks * 32 + (e0 >> 2) * 16 + g * 4 + (e0 & 3);
                int dim1 = ks * 32 + (e1 >> 2) * 16 + g * 4 + (e1 & 3);
                float f0 = W0[(k * BASIS + dim0) * 16 + col];
                float f1 = W0[(k * BASIS + dim1) * 16 + col];
                wv[i] = cvt_pk_bf16(f0, f1);
            }
            w0f[ks] = __builtin_bit_cast(bf16x8, wv);
        }
        bf16x8 w1f;         // A = W1^T padded to K=32 (elems e>=4 zero)
        {
            i32x4 wv;
            float a0 = (col < 4) ? W1[(k * 16 + g * 4 + 0) * 4 + col] : 0.0f;
            float a1 = (col < 4) ? W1[(k * 16 + g * 4 + 1) * 4 + col] : 0.0f;
            float a2 = (col < 4) ? W1[(k * 16 + g * 4 + 2) * 4 + col] : 0.0f;
            float a3 = (col < 4) ? W1[(k * 16 + g * 4 + 3) * 4 + col] : 0.0f;
            wv[0] = cvt_pk_bf16(a0, a1);
            wv[1] = cvt_pk_bf16(a2, a3);
            wv[2] = 0; wv[3] = 0;
            w1f = __builtin_bit_cast(bf16x8, wv);
        }
        f32x4 b0v = *(const f32x4*)(b0 + k * 16 + g * 4);
        const float* b1k = b1 + k * 4;
        const float* W2k = W2 + k * 4;

        // ---- dist/env/diff phase ----
        {
            float dx = s_xs[q][pj0 * 3 + 0] - s_xs[q][pi0 * 3 + 0];
            float dy = s_xs[q][pj0 * 3 + 1] - s_xs[q][pi0 * 3 + 1];
            float dz = s_xs[q][pj0 * 3 + 2] - s_xs[q][pi0 * 3 + 2];
            float dist = sqrtf(fmaf(dx, dx, fmaf(dy, dy, dz * dz)));
            float x = dist * (1.0f / CUTOFF);
            float env = 0.0f;
            if (x <= 1.0f) {
                float pp = fmaf(-6.0f, x, 15.0f);
                pp = fmaf(pp, x, -10.0f);
                env = fmaf(x * x * x, pp, 1.0f);
            }
            s_dd[q][lane] = (f32x2){dist, env};
            s_df[q][lane] = (f32x4){dx, dy, dz, 0.0f};
        }
        if (lane < 48) {
            if (lane < 41) {
                int p = 64 + lane;
                float dx = s_xs[q][pj1 * 3 + 0] - s_xs[q][pi1 * 3 + 0];
                float dy = s_xs[q][pj1 * 3 + 1] - s_xs[q][pi1 * 3 + 1];
                float dz = s_xs[q][pj1 * 3 + 2] - s_xs[q][pi1 * 3 + 2];
                float dist = sqrtf(fmaf(dx, dx, fmaf(dy, dy, dz * dz)));
                float x = dist * (1.0f / CUTOFF);
                float env = 0.0f;
                if (x <= 1.0f) {
                    float pp = fmaf(-6.0f, x, 15.0f);
                    pp = fmaf(pp, x, -10.0f);
                    env = fmaf(x * x * x, pp, 1.0f);
                }
                s_dd[q][p] = (f32x2){dist, env};
                s_df[q][p] = (f32x4){dx, dy, dz, 0.0f};
            } else {
                s_dd[q][64 + lane] = (f32x2){2.0f * CUTOFF, 0.0f};
            }
        }

        // ---- 7 tiles of 16 pairs ----
        for (int t = 0; t < 7; ++t) {
            f32x2 de = s_dd[q][t * 16 + col];
            float dist = de.x, env = de.y;

            // env multiplies the MFMA output, so if ALL 16 pairs of this tile
            // are beyond cutoff (env==0), the basis + layer-0 MFMAs are dead.
            // Wave-uniform branch: exact skip, no divergence.
            f32x4 acc = {0.0f, 0.0f, 0.0f, 0.0f};
            if (!__all(env == 0.0f)) {
                f32x2 d2 = {dist, dist};
                bf16x8 bfrag[2];
                #pragma unroll
                for (int ks = 0; ks < 2; ++ks) {
                    i32x4 wd;
                    #pragma unroll
                    for (int p = 0; p < 4; ++p) {
                        f32x2 tt = d2 - mu2[ks * 4 + p];
                        f32x2 a  = (tt * tt) * is2[ks * 4 + p];
                        float e0 = __builtin_amdgcn_exp2f(a.x);
                        float e1 = __builtin_amdgcn_exp2f(a.y);
                        wd[p] = cvt_pk_bf16(e0, e1);
                    }
                    bfrag[ks] = __builtin_bit_cast(bf16x8, wd);
                }
                // layer 0: D[ch][pair] = W0^T . E^T  (fp32 accumulate)
                acc = __builtin_amdgcn_mfma_f32_16x16x32_bf16(w0f[0], bfrag[0], acc, 0, 0, 0);
                acc = __builtin_amdgcn_mfma_f32_16x16x32_bf16(w0f[1], bfrag[1], acc, 0, 0, 0);
            }

            // h1 = ssp(env*acc + b0) -> bf16 B-fragment (env fold = free fma)
            i32x4 hw;
            hw[0] = cvt_pk_bf16(ssp(fmaf(env, acc[0], b0v[0])),
                                ssp(fmaf(env, acc[1], b0v[1])));
            hw[1] = cvt_pk_bf16(ssp(fmaf(env, acc[2], b0v[2])),
                                ssp(fmaf(env, acc[3], b0v[3])));
            hw[2] = 0; hw[3] = 0;   // K=16..31 must be numeric (0*NaN = NaN)
            bf16x8 hb = __builtin_bit_cast(bf16x8, hw);

            // layer 1: D2[e_out][pair] = W1^T . H1s
            f32x4 a2 = {0.0f, 0.0f, 0.0f, 0.0f};
            a2 = __builtin_amdgcn_mfma_f32_16x16x32_bf16(w1f, hb, a2, 0, 0, 0);

            if (g == 0) s_h2[q][t * 16 + col] = a2;   // raw; finished in batch below
        }

        // ---- batched epilogue: w = sum_r ssp(a2[r]+b1[r])*W2[r]; s_df *= w ----
        #pragma unroll
        for (int it = 0; it < 2; ++it) {
            int p = it * 64 + lane;
            if (it == 0 || lane < 41) {
                f32x4 a2 = s_h2[q][p];
                float w = ssp(a2[0] + b1k[0]) * W2k[0];
                w = fmaf(ssp(a2[1] + b1k[1]), W2k[1], w);
                w = fmaf(ssp(a2[2] + b1k[2]), W2k[2], w);
                w = fmaf(ssp(a2[3] + b1k[3]), W2k[3], w);
                f32x4 df = s_df[q][p];
                s_df[q][p] = (f32x4){w * df.x, w * df.y, w * df.z, 0.0f};
            }
        }

        // ---- scatter-reduce: xs[e] += sum_j +/- w*diff ----
        if (lane < 45) {
            int e = lane / 3, dim = lane - 3 * e;
            const float* wd = (const float*)&s_df[q][0];
            float acc = 0.0f;
            int offe = e * (2 * N_EL - e - 1) / 2;
            for (int j = e + 1; j < N_EL; ++j)
                acc += wd[(offe + j - e - 1) * 4 + dim];
            for (int i2 = 0; i2 < e; ++i2) {
                int p = i2 * (2 * N_EL - i2 - 1) / 2 + (e - i2 - 1);
                acc -= wd[p * 4 + dim];
            }
            s_xs[q][lane] += acc;
        }
    }

    if (lane < 45) out[prob * 45 + lane] = s_xs[q][lane];
}

extern "C" void kernel_launch(void* const* d_in, const int* in_sizes, int n_in,
                              void* d_out, int out_size, void* d_ws, size_t ws_size,
                              hipStream_t stream) {
    const float* rs = (const float*)d_in[0];
    const float* W0 = (const float*)d_in[1];
    const float* b0 = (const float*)d_in[2];
    const float* W1 = (const float*)d_in[3];
    const float* b1 = (const float*)d_in[4];
    const float* W2 = (const float*)d_in[5];
    float* out = (float*)d_out;

    const int nprob = 4096 * 2;                   // (batch, spin) problems
    dim3 grid(nprob / WPB);                       // 2048 blocks
    dim3 block(NTHR);
    hipLaunchKernelGGL(backflow_kernel, grid, block, 0, stream,
                       rs, W0, b0, W1, b1, W2, out);
}